// Round 1
// baseline (813.083 us; speedup 1.0000x reference)
//
#include <hip/hip_runtime.h>
#include <stdint.h>

typedef __attribute__((ext_vector_type(8))) short short8v;
typedef __attribute__((ext_vector_type(4))) float f32x4;

#define ATTN_NORM 0.13363062095621219f
#define LOG2E 1.4426950408889634f

__device__ __forceinline__ unsigned short f2bf(float f) {
  union { float f; uint32_t u; } v; v.f = f;
  uint32_t u = v.u;
  u += 0x7fffu + ((u >> 16) & 1u);
  return (unsigned short)(u >> 16);
}

// ---------------- prep: W[m][n] fp32 -> W_T[n][m] bf16, scales folded ----------------
// ws layout (bf16 elements): mat-major (q,k,v), within mat l0(65536), l1(16384), l2(4096)
__global__ void prep_w(const float* q0, const float* q1, const float* q2,
                       const float* k0, const float* k1, const float* k2,
                       const float* v0, const float* v1, const float* v2,
                       unsigned short* ws) {
  int e = blockIdx.x * 256 + threadIdx.x;
  if (e >= 258048) return;
  int mat = e / 86016;
  int r = e - mat * 86016;
  int li, base, mul;
  if (r < 65536)      { li = 0; base = 0;     mul = 256; }
  else if (r < 81920) { li = 1; base = 65536; mul = 128; }
  else                { li = 2; base = 81920; mul = 64;  }
  int idx = r - base;
  int n = idx / mul, m = idx - n * mul;
  const float* src;
  if (mat == 0)      src = (li == 0) ? q0 : (li == 1) ? q1 : q2;
  else if (mat == 1) src = (li == 0) ? k0 : (li == 1) ? k1 : k2;
  else               src = (li == 0) ? v0 : (li == 1) ? v1 : v2;
  float rsqm = (li == 0) ? 0.0625f : (li == 1) ? 0.08838834764831845f : 0.125f;
  float scale = rsqm;
  if (mat == 0) {
    float qext = (li == 0) ? 1.0f : (li == 1) ? 0.5773502691896258f : 0.4472135954999579f;
    scale *= ATTN_NORM * LOG2E * qext;
  }
  ws[e] = f2bf(src[m * mul + n] * scale);
}

// ---------------- per-l QKV phase ----------------
// X staged per K-chunk as A-layout: row r = i*64 + q, col m (chunk-local), bf16, XOR-swizzled.
// Q/K written to [64 tok][128 ch] head-layout; V written transposed [128 ch][64 tok].
template<int MUL, int D, int NPL, int NTC, int COFF, int XOFF, int RSW>
__device__ __forceinline__ void do_l(const float* __restrict__ xb,
                                     const unsigned short* __restrict__ wq,
                                     const unsigned short* __restrict__ wk,
                                     const unsigned short* __restrict__ wv_,
                                     char* sX, char* sQ, char* sK, char* sVT,
                                     int h, int tid) {
  const int lane = tid & 63;
  const int wvi = tid >> 6;
  const int l15 = lane & 15;
  const int blk = lane >> 4;
  constexpr int CHC = MUL / 2;   // chunk columns (m)
  constexpr int ROWB = CHC * 2;  // bytes per LDS X row
  constexpr int KS = CHC / 32;   // K32 MFMA steps per chunk
  constexpr int CNT = CHC * D;   // x channels per token per chunk

  f32x4 acc[3][NTC][D];
  #pragma unroll
  for (int a = 0; a < 3; ++a)
    #pragma unroll
    for (int bb = 0; bb < NTC; ++bb)
      #pragma unroll
      for (int c = 0; c < D; ++c)
        acc[a][bb][c] = (f32x4){0.f, 0.f, 0.f, 0.f};

  #pragma unroll
  for (int c2 = 0; c2 < 2; ++c2) {
    // ---- stage x chunk (fp32 global -> bf16 LDS, A-layout, swizzled)
    for (int f = tid; f < 64 * CNT / 4; f += 256) {
      int q = f / (CNT / 4);
      int j4 = (f - q * (CNT / 4)) * 4;
      float4 v = *(const float4*)(xb + q * 960 + XOFF + c2 * CNT + j4);
      const float vv[4] = {v.x, v.y, v.z, v.w};
      #pragma unroll
      for (int e = 0; e < 4; ++e) {
        int jl = j4 + e;
        int m = jl / D, i = jl - m * D;
        int row = i * 64 + q;
        int bc = m * 2;
        *(unsigned short*)(sX + row * ROWB + (bc ^ ((row & RSW) << 4))) = f2bf(vv[e]);
      }
    }
    __syncthreads();
    // ---- MFMA: C[r][n] = sum_m X[r][m] * W[m][n]
    #pragma unroll
    for (int mat = 0; mat < 3; ++mat) {
      const unsigned short* wp = (mat == 0) ? wq : (mat == 1) ? wk : wv_;
      #pragma unroll
      for (int nt = 0; nt < NTC; ++nt) {
        int n = h * NPL + nt * 16 + l15;
        if (n > MUL - 1) n = MUL - 1;  // l=2 pad cols, discarded on write
        for (int ks = 0; ks < KS; ++ks) {
          int mcol = c2 * CHC + ks * 32 + blk * 8;
          short8v bfr = *(const short8v*)(wp + n * MUL + mcol);
          #pragma unroll
          for (int j = 0; j < D; ++j) {
            int rt = wvi + 4 * j;
            int row = rt * 16 + l15;
            int bc = (ks * 32 + blk * 8) * 2;
            short8v afr = *(const short8v*)(sX + row * ROWB + (bc ^ ((row & RSW) << 4)));
            acc[mat][nt][j] = __builtin_amdgcn_mfma_f32_16x16x32_bf16(afr, bfr, acc[mat][nt][j], 0, 0, 0);
          }
        }
      }
    }
    __syncthreads();
  }
  // ---- write Q/K/V fragments to LDS head-layout
  #pragma unroll
  for (int mat = 0; mat < 3; ++mat) {
    #pragma unroll
    for (int nt = 0; nt < NTC; ++nt) {
      int nl = nt * 16 + l15;
      bool valid = (nl < NPL);
      #pragma unroll
      for (int j = 0; j < D; ++j) {
        int rt = wvi + 4 * j;
        int i = (rt * 16) >> 6;
        int c = COFF + nl * D + i;
        #pragma unroll
        for (int reg = 0; reg < 4; ++reg) {
          int r = rt * 16 + blk * 4 + reg;
          int q = r & 63;
          if (valid) {
            unsigned short bv = f2bf(acc[mat][nt][j][reg]);
            if (mat == 0)
              *(unsigned short*)(sQ + q * 256 + ((c * 2) ^ ((q & 7) << 4))) = bv;
            else if (mat == 1)
              *(unsigned short*)(sK + q * 256 + ((c * 2) ^ ((q & 7) << 4))) = bv;
            else
              *(unsigned short*)(sVT + c * 128 + ((q * 2) ^ ((c & 7) << 4))) = bv;
          }
        }
      }
    }
  }
}

// ---------------- main kernel: one WG per (batch, head) ----------------
__launch_bounds__(256, 2)
__global__ void orbattn(const float* __restrict__ x,
                        const unsigned short* __restrict__ ws,
                        float* __restrict__ out) {
  extern __shared__ char smem[];
  char* sX  = smem;           // 24576 B (max chunk: l=1 [192][64])
  char* sQ  = smem + 24576;   // [64][128] bf16 = 16384
  char* sK  = smem + 40960;   // 16384
  char* sVT = smem + 57344;   // [128][64] bf16 = 16384
  char* sP  = smem + 73728;   // [64][64] bf16 = 8192    total 81920
  int tid = threadIdx.x;
  int bid = blockIdx.x;
  // XCD-grouped mapping: all 8 heads of a batch on the same XCD (x[b] L2 reuse)
  int xcd = bid & 7, t = bid >> 3;
  int h = t & 7;
  int b = (t >> 3) * 8 + xcd;
  const float* xb = x + (size_t)b * 61440;
  float* ob = out + (size_t)b * 61440;
  const int lane = tid & 63, wvi = tid >> 6, l15 = lane & 15, blk = lane >> 4;

  // zero pad channels 120..127 of Q,K (read by logits ks=3 step)
  for (int f = tid; f < 512; f += 256) {
    int q = f >> 3, c = 120 + (f & 7);
    *(unsigned short*)(sQ + q * 256 + ((c * 2) ^ ((q & 7) << 4))) = 0;
    *(unsigned short*)(sK + q * 256 + ((c * 2) ^ ((q & 7) << 4))) = 0;
  }

  do_l<256, 1, 32, 2,  0,   0, 7>(xb, ws,          ws + 86016,  ws + 172032, sX, sQ, sK, sVT, h, tid);
  do_l<128, 3, 16, 1, 32, 256, 7>(xb, ws + 65536,  ws + 151552, ws + 237568, sX, sQ, sK, sVT, h, tid);
  do_l< 64, 5,  8, 1, 80, 640, 3>(xb, ws + 81920,  ws + 167936, ws + 253952, sX, sQ, sK, sVT, h, tid);
  __syncthreads();

  // ---- logits: S[q][k] = sum_c Q[q][c] K[k][c]  (wave w owns q-tile w)
  f32x4 lacc[4];
  #pragma unroll
  for (int kt = 0; kt < 4; ++kt) lacc[kt] = (f32x4){0.f, 0.f, 0.f, 0.f};
  #pragma unroll
  for (int ks = 0; ks < 4; ++ks) {
    int qr = wvi * 16 + l15;
    int bc = (ks * 32 + blk * 8) * 2;
    short8v qf = *(const short8v*)(sQ + qr * 256 + (bc ^ ((qr & 7) << 4)));
    #pragma unroll
    for (int kt = 0; kt < 4; ++kt) {
      int kr = kt * 16 + l15;
      short8v kf = *(const short8v*)(sK + kr * 256 + (bc ^ ((kr & 7) << 4)));
      lacc[kt] = __builtin_amdgcn_mfma_f32_16x16x32_bf16(qf, kf, lacc[kt], 0, 0, 0);
    }
  }
  // ---- softmax over k (exp2; LOG2E folded into wq) + write P bf16
  #pragma unroll
  for (int reg = 0; reg < 4; ++reg) {
    float mx = fmaxf(fmaxf(lacc[0][reg], lacc[1][reg]), fmaxf(lacc[2][reg], lacc[3][reg]));
    #pragma unroll
    for (int dd = 1; dd <= 8; dd <<= 1) mx = fmaxf(mx, __shfl_xor(mx, dd, 64));
    float p[4], s = 0.f;
    #pragma unroll
    for (int kt = 0; kt < 4; ++kt) { p[kt] = exp2f(lacc[kt][reg] - mx); s += p[kt]; }
    #pragma unroll
    for (int dd = 1; dd <= 8; dd <<= 1) s += __shfl_xor(s, dd, 64);
    float inv = 1.0f / s;
    int q = wvi * 16 + blk * 4 + reg;
    #pragma unroll
    for (int kt = 0; kt < 4; ++kt) {
      int k = kt * 16 + l15;
      *(unsigned short*)(sP + q * 128 + ((k * 2) ^ ((q & 7) << 4))) = f2bf(p[kt] * inv);
    }
  }
  __syncthreads();

  // ---- PV: U[q][c] = sum_k P[q][k] V_T[c][k]
  f32x4 uacc[8];
  #pragma unroll
  for (int ct = 0; ct < 8; ++ct) uacc[ct] = (f32x4){0.f, 0.f, 0.f, 0.f};
  #pragma unroll
  for (int ks = 0; ks < 2; ++ks) {
    int qr = wvi * 16 + l15;
    int bc = (ks * 32 + blk * 8) * 2;
    short8v pf = *(const short8v*)(sP + qr * 128 + (bc ^ ((qr & 7) << 4)));
    #pragma unroll
    for (int ct = 0; ct < 8; ++ct) {
      int cr = ct * 16 + l15;
      short8v vf = *(const short8v*)(sVT + cr * 128 + (bc ^ ((cr & 7) << 4)));
      uacc[ct] = __builtin_amdgcn_mfma_f32_16x16x32_bf16(pf, vf, uacc[ct], 0, 0, 0);
    }
  }
  // ---- epilogue: out = x + update (axis_to_mul channel mapping)
  #pragma unroll
  for (int ct = 0; ct < 8; ++ct) {
    int c = ct * 16 + l15;
    if (c < 120) {
      int o;
      if (c < 32) o = h * 32 + c;
      else if (c < 80) { int cc = c - 32; int nl = cc / 3, i = cc - nl * 3; o = 256 + (h * 16 + nl) * 3 + i; }
      else             { int cc = c - 80; int nl = cc / 5, i = cc - nl * 5; o = 640 + (h * 8 + nl) * 5 + i; }
      #pragma unroll
      for (int reg = 0; reg < 4; ++reg) {
        int q = wvi * 16 + blk * 4 + reg;
        int gi = q * 960 + o;
        ob[gi] = xb[gi] + uacc[ct][reg];
      }
    }
  }
}

extern "C" void kernel_launch(void* const* d_in, const int* in_sizes, int n_in,
                              void* d_out, int out_size, void* d_ws, size_t ws_size,
                              hipStream_t stream) {
  const float* x = (const float*)d_in[0];
  unsigned short* ws = (unsigned short*)d_ws;  // needs >= 516096 bytes
  float* out = (float*)d_out;
  hipFuncSetAttribute((const void*)orbattn, hipFuncAttributeMaxDynamicSharedMemorySize, 81920);
  prep_w<<<(258048 + 255) / 256, 256, 0, stream>>>(
      (const float*)d_in[1], (const float*)d_in[2], (const float*)d_in[3],
      (const float*)d_in[4], (const float*)d_in[5], (const float*)d_in[6],
      (const float*)d_in[7], (const float*)d_in[8], (const float*)d_in[9], ws);
  orbattn<<<8192, 256, 81920, stream>>>(x, ws, out);
}

// Round 2
// 498.235 us; speedup vs baseline: 1.6319x; 1.6319x over previous
//
#include <hip/hip_runtime.h>
#include <stdint.h>

typedef __attribute__((ext_vector_type(8))) short short8v;
typedef __attribute__((ext_vector_type(4))) unsigned short ushort4v;
typedef __attribute__((ext_vector_type(4))) float f32x4;
typedef __attribute__((ext_vector_type(4))) int int4v;

#define ATTN_NORM 0.13363062095621219f
#define LOG2E 1.4426950408889634f

__device__ __forceinline__ unsigned short f2bf(float f) {
  union { float f; uint32_t u; } v; v.f = f;
  uint32_t u = v.u;
  u += 0x7fffu + ((u >> 16) & 1u);
  return (unsigned short)(u >> 16);
}

__device__ __forceinline__ void gload_lds16(const char* g, char* l) {
  __builtin_amdgcn_global_load_lds(
      (const __attribute__((address_space(1))) void*)g,
      (__attribute__((address_space(3))) void*)l, 16, 0, 0);
}

// ---------------- prep: W[m][n] fp32 -> W_T[n][m] bf16, scales folded ----------------
__global__ void prep_w(const float* q0, const float* q1, const float* q2,
                       const float* k0, const float* k1, const float* k2,
                       const float* v0, const float* v1, const float* v2,
                       unsigned short* ws) {
  int e = blockIdx.x * 256 + threadIdx.x;
  if (e >= 258048) return;
  int mat = e / 86016;
  int r = e - mat * 86016;
  int li, base, mul;
  if (r < 65536)      { li = 0; base = 0;     mul = 256; }
  else if (r < 81920) { li = 1; base = 65536; mul = 128; }
  else                { li = 2; base = 81920; mul = 64;  }
  int idx = r - base;
  int n = idx / mul, m = idx - n * mul;
  const float* src;
  if (mat == 0)      src = (li == 0) ? q0 : (li == 1) ? q1 : q2;
  else if (mat == 1) src = (li == 0) ? k0 : (li == 1) ? k1 : k2;
  else               src = (li == 0) ? v0 : (li == 1) ? v1 : v2;
  float rsqm = (li == 0) ? 0.0625f : (li == 1) ? 0.08838834764831845f : 0.125f;
  float scale = rsqm;
  if (mat == 0) {
    float qext = (li == 0) ? 1.0f : (li == 1) ? 0.5773502691896258f : 0.4472135954999579f;
    scale *= ATTN_NORM * LOG2E * qext;
  }
  ws[e] = f2bf(src[m * mul + n] * scale);
}

// ---------------- convert x -> per-batch bf16 LDS-image (pre-transposed + swizzled) ----
// image per batch (122880 B): [l0c0 16384][l0c1 16384][l1c0 24576][l1c1 24576][l2c0 20480][l2c1 20480]
template<int CHC, int D, int XO, int RSW, int IMGOFF>
__device__ __forceinline__ void conv_chunk(const float* __restrict__ xb, char* dstb,
                                           char* sX, int tid) {
  constexpr int ROWB = CHC * 2, CNT = CHC * D, NB = 64 * D * ROWB;
  for (int f = tid; f < 64 * CNT / 4; f += 256) {
    int q = f / (CNT / 4);
    int j4 = (f - q * (CNT / 4)) * 4;
    float4 v = *(const float4*)(xb + q * 960 + XO + j4);
    const float vv[4] = {v.x, v.y, v.z, v.w};
    #pragma unroll
    for (int e = 0; e < 4; ++e) {
      int jl = j4 + e;
      int m = jl / D, i = jl - m * D;
      int row = i * 64 + q;
      *(unsigned short*)(sX + row * ROWB + ((m * 2) ^ ((row & RSW) << 4))) = f2bf(vv[e]);
    }
  }
  __syncthreads();
  for (int f = tid; f < NB / 16; f += 256)
    *(int4v*)(dstb + IMGOFF + f * 16) = *(const int4v*)(sX + f * 16);
  __syncthreads();
}

__global__ void conv_x(const float* __restrict__ x, unsigned short* xw) {
  __shared__ char sX[24576];
  int b = blockIdx.x, tid = threadIdx.x;
  const float* xb = x + (size_t)b * 61440;
  char* dstb = (char*)xw + (size_t)b * 122880;
  conv_chunk<128, 1,   0, 7,      0>(xb, dstb, sX, tid);
  conv_chunk<128, 1, 128, 7,  16384>(xb, dstb, sX, tid);
  conv_chunk< 64, 3, 256, 7,  32768>(xb, dstb, sX, tid);
  conv_chunk< 64, 3, 448, 7,  57344>(xb, dstb, sX, tid);
  conv_chunk< 32, 5, 640, 3,  81920>(xb, dstb, sX, tid);
  conv_chunk< 32, 5, 800, 3, 102400>(xb, dstb, sX, tid);
}

// ---------------- per-l QKV phase (fast path): A=W_T, B=X -> acc holds 4 consec channels
template<int MUL, int D, int NPL, int COFF, int IMGOFF, int RSW>
__device__ __forceinline__ void do_l2(const char* __restrict__ xwb,
                                      const unsigned short* __restrict__ wq,
                                      const unsigned short* __restrict__ wk,
                                      const unsigned short* __restrict__ wv_,
                                      char* sX, char* sQ, char* sK, char* sVT,
                                      int h, int tid) {
  const int lane = tid & 63, wvi = tid >> 6, l15 = lane & 15, blk = lane >> 4;
  constexpr int CHC = MUL / 2, ROWB = CHC * 2, KS = CHC / 32;
  constexpr int CHB = 64 * D * ROWB;
  constexpr int NT = (NPL + 15) / 16;

  f32x4 acc[3][NT][D];
  #pragma unroll
  for (int a = 0; a < 3; ++a)
    #pragma unroll
    for (int t = 0; t < NT; ++t)
      #pragma unroll
      for (int j = 0; j < D; ++j)
        acc[a][t][j] = (f32x4){0.f, 0.f, 0.f, 0.f};

  #pragma unroll
  for (int c2 = 0; c2 < 2; ++c2) {
    const char* gsrc = xwb + IMGOFF + c2 * CHB;
    #pragma unroll
    for (int it = 0; it < CHB / 4096; ++it)
      gload_lds16(gsrc + it * 4096 + wvi * 1024 + lane * 16,
                  sX + it * 4096 + wvi * 1024);
    __syncthreads();
    #pragma unroll
    for (int mat = 0; mat < 3; ++mat) {
      const unsigned short* wp = (mat == 0) ? wq : (mat == 1) ? wk : wv_;
      #pragma unroll
      for (int nt = 0; nt < NT; ++nt) {
        int nin = nt * 16 + ((NPL < 16 && l15 >= NPL) ? (NPL - 1) : l15);
        int n = h * NPL + nin;
        #pragma unroll
        for (int ks = 0; ks < KS; ++ks) {
          short8v wfr = *(const short8v*)(wp + n * MUL + c2 * CHC + ks * 32 + blk * 8);
          #pragma unroll
          for (int j = 0; j < D; ++j) {
            int row = (wvi + 4 * j) * 16 + l15;
            int bc = (ks * 32 + blk * 8) * 2;
            short8v xfr = *(const short8v*)(sX + row * ROWB + (bc ^ ((row & RSW) << 4)));
            acc[mat][nt][j] = __builtin_amdgcn_mfma_f32_16x16x32_bf16(wfr, xfr, acc[mat][nt][j], 0, 0, 0);
          }
        }
      }
    }
    __syncthreads();
  }
  // write Q/K packed (4 consecutive channels per lane), V transposed scalar
  #pragma unroll
  for (int nt = 0; nt < NT; ++nt) {
    #pragma unroll
    for (int j = 0; j < D; ++j) {
      int rtile = wvi + 4 * j;
      int i = rtile >> 2;
      int q = (rtile & 3) * 16 + l15;
      int cb = COFF + i * NPL + nt * 16 + blk * 4;
      bool valid = (NPL >= 16) || (blk * 4 < NPL);
      if (valid) {
        ushort4v pq = {f2bf(acc[0][nt][j][0]), f2bf(acc[0][nt][j][1]),
                       f2bf(acc[0][nt][j][2]), f2bf(acc[0][nt][j][3])};
        ushort4v pk = {f2bf(acc[1][nt][j][0]), f2bf(acc[1][nt][j][1]),
                       f2bf(acc[1][nt][j][2]), f2bf(acc[1][nt][j][3])};
        int sw = (cb * 2) ^ ((q & 7) << 4);
        *(ushort4v*)(sQ + q * 256 + sw) = pq;
        *(ushort4v*)(sK + q * 256 + sw) = pk;
        #pragma unroll
        for (int reg = 0; reg < 4; ++reg) {
          int c = cb + reg;
          *(unsigned short*)(sVT + c * 128 + ((q * 2) ^ ((c & 7) << 4))) = f2bf(acc[2][nt][j][reg]);
        }
      }
    }
  }
}

// ---------------- main attention kernel (fast path) ----------------
__launch_bounds__(256, 2)
__global__ void orbattn2(const float* __restrict__ x,
                         const unsigned short* __restrict__ ws,
                         const unsigned short* __restrict__ xw,
                         float* __restrict__ out) {
  extern __shared__ char smem[];
  char* sX  = smem;           // 24576 (chunk staging; later reused for P)
  char* sQ  = smem + 24576;   // [64][128] bf16
  char* sK  = smem + 40960;
  char* sVT = smem + 57344;   // [128][64] bf16
  char* sP  = smem;           // overlaps sX
  int tid = threadIdx.x;
  int bid = blockIdx.x;
  int xcd = bid & 7, t = bid >> 3;
  int h = t & 7;
  int b = (t >> 3) * 8 + xcd;
  const float* xb = x + (size_t)b * 61440;
  float* ob = out + (size_t)b * 61440;
  const char* xwb = (const char*)xw + (size_t)b * 122880;
  const int lane = tid & 63, wvi = tid >> 6, l15 = lane & 15, blk = lane >> 4;

  // zero pad channels 120..127 of Q,K
  for (int f = tid; f < 512; f += 256) {
    int q = f >> 3, c = 120 + (f & 7);
    *(unsigned short*)(sQ + q * 256 + ((c * 2) ^ ((q & 7) << 4))) = 0;
    *(unsigned short*)(sK + q * 256 + ((c * 2) ^ ((q & 7) << 4))) = 0;
  }

  do_l2<256, 1, 32,  0,     0, 7>(xwb, ws,         ws + 86016,  ws + 172032, sX, sQ, sK, sVT, h, tid);
  do_l2<128, 3, 16, 32, 32768, 7>(xwb, ws + 65536, ws + 151552, ws + 237568, sX, sQ, sK, sVT, h, tid);
  do_l2< 64, 5,  8, 80, 81920, 3>(xwb, ws + 81920, ws + 167936, ws + 253952, sX, sQ, sK, sVT, h, tid);
  __syncthreads();

  // ---- logits
  f32x4 lacc[4];
  #pragma unroll
  for (int kt = 0; kt < 4; ++kt) lacc[kt] = (f32x4){0.f, 0.f, 0.f, 0.f};
  #pragma unroll
  for (int ks = 0; ks < 4; ++ks) {
    int qr = wvi * 16 + l15;
    int bc = (ks * 32 + blk * 8) * 2;
    short8v qf = *(const short8v*)(sQ + qr * 256 + (bc ^ ((qr & 7) << 4)));
    #pragma unroll
    for (int kt = 0; kt < 4; ++kt) {
      int kr = kt * 16 + l15;
      short8v kf = *(const short8v*)(sK + kr * 256 + (bc ^ ((kr & 7) << 4)));
      lacc[kt] = __builtin_amdgcn_mfma_f32_16x16x32_bf16(qf, kf, lacc[kt], 0, 0, 0);
    }
  }
  // ---- softmax (exp2; LOG2E folded into wq)
  #pragma unroll
  for (int reg = 0; reg < 4; ++reg) {
    float mx = fmaxf(fmaxf(lacc[0][reg], lacc[1][reg]), fmaxf(lacc[2][reg], lacc[3][reg]));
    #pragma unroll
    for (int dd = 1; dd <= 8; dd <<= 1) mx = fmaxf(mx, __shfl_xor(mx, dd, 64));
    float p[4], s = 0.f;
    #pragma unroll
    for (int kt = 0; kt < 4; ++kt) { p[kt] = exp2f(lacc[kt][reg] - mx); s += p[kt]; }
    #pragma unroll
    for (int dd = 1; dd <= 8; dd <<= 1) s += __shfl_xor(s, dd, 64);
    float inv = 1.0f / s;
    int q = wvi * 16 + blk * 4 + reg;
    #pragma unroll
    for (int kt = 0; kt < 4; ++kt) {
      int k = kt * 16 + l15;
      *(unsigned short*)(sP + q * 128 + ((k * 2) ^ ((q & 7) << 4))) = f2bf(p[kt] * inv);
    }
  }
  __syncthreads();

  // ---- PV
  f32x4 uacc[8];
  #pragma unroll
  for (int ct = 0; ct < 8; ++ct) uacc[ct] = (f32x4){0.f, 0.f, 0.f, 0.f};
  #pragma unroll
  for (int ks = 0; ks < 2; ++ks) {
    int qr = wvi * 16 + l15;
    int bc = (ks * 32 + blk * 8) * 2;
    short8v pf = *(const short8v*)(sP + qr * 128 + (bc ^ ((qr & 7) << 4)));
    #pragma unroll
    for (int ct = 0; ct < 8; ++ct) {
      int cr = ct * 16 + l15;
      short8v vf = *(const short8v*)(sVT + cr * 128 + (bc ^ ((cr & 7) << 4)));
      uacc[ct] = __builtin_amdgcn_mfma_f32_16x16x32_bf16(pf, vf, uacc[ct], 0, 0, 0);
    }
  }
  // ---- epilogue (i-major channel map)
  #pragma unroll
  for (int ct = 0; ct < 8; ++ct) {
    int c = ct * 16 + l15;
    if (c < 120) {
      int o;
      if (c < 32) o = h * 32 + c;
      else if (c < 80) { int cc = c - 32; int i = cc >> 4, nl = cc & 15; o = 256 + (h * 16 + nl) * 3 + i; }
      else             { int cc = c - 80; int i = cc >> 3, nl = cc & 7;  o = 640 + (h * 8 + nl) * 5 + i; }
      #pragma unroll
      for (int reg = 0; reg < 4; ++reg) {
        int q = wvi * 16 + blk * 4 + reg;
        int gi = q * 960 + o;
        ob[gi] = xb[gi] + uacc[ct][reg];
      }
    }
  }
}

// ================= FALLBACK (round-1) path: used if ws too small =================
template<int MUL, int D, int NPL, int NTC, int COFF, int XOFF, int RSW>
__device__ __forceinline__ void do_l_fb(const float* __restrict__ xb,
                                        const unsigned short* __restrict__ wq,
                                        const unsigned short* __restrict__ wk,
                                        const unsigned short* __restrict__ wv_,
                                        char* sX, char* sQ, char* sK, char* sVT,
                                        int h, int tid) {
  const int lane = tid & 63;
  const int wvi = tid >> 6;
  const int l15 = lane & 15;
  const int blk = lane >> 4;
  constexpr int CHC = MUL / 2;
  constexpr int ROWB = CHC * 2;
  constexpr int KS = CHC / 32;
  constexpr int CNT = CHC * D;

  f32x4 acc[3][NTC][D];
  #pragma unroll
  for (int a = 0; a < 3; ++a)
    #pragma unroll
    for (int bb = 0; bb < NTC; ++bb)
      #pragma unroll
      for (int c = 0; c < D; ++c)
        acc[a][bb][c] = (f32x4){0.f, 0.f, 0.f, 0.f};

  #pragma unroll
  for (int c2 = 0; c2 < 2; ++c2) {
    for (int f = tid; f < 64 * CNT / 4; f += 256) {
      int q = f / (CNT / 4);
      int j4 = (f - q * (CNT / 4)) * 4;
      float4 v = *(const float4*)(xb + q * 960 + XOFF + c2 * CNT + j4);
      const float vv[4] = {v.x, v.y, v.z, v.w};
      #pragma unroll
      for (int e = 0; e < 4; ++e) {
        int jl = j4 + e;
        int m = jl / D, i = jl - m * D;
        int row = i * 64 + q;
        int bc = m * 2;
        *(unsigned short*)(sX + row * ROWB + (bc ^ ((row & RSW) << 4))) = f2bf(vv[e]);
      }
    }
    __syncthreads();
    #pragma unroll
    for (int mat = 0; mat < 3; ++mat) {
      const unsigned short* wp = (mat == 0) ? wq : (mat == 1) ? wk : wv_;
      #pragma unroll
      for (int nt = 0; nt < NTC; ++nt) {
        int n = h * NPL + nt * 16 + l15;
        if (n > MUL - 1) n = MUL - 1;
        for (int ks = 0; ks < KS; ++ks) {
          int mcol = c2 * CHC + ks * 32 + blk * 8;
          short8v bfr = *(const short8v*)(wp + n * MUL + mcol);
          #pragma unroll
          for (int j = 0; j < D; ++j) {
            int rt = wvi + 4 * j;
            int row = rt * 16 + l15;
            int bc = (ks * 32 + blk * 8) * 2;
            short8v afr = *(const short8v*)(sX + row * ROWB + (bc ^ ((row & RSW) << 4)));
            acc[mat][nt][j] = __builtin_amdgcn_mfma_f32_16x16x32_bf16(afr, bfr, acc[mat][nt][j], 0, 0, 0);
          }
        }
      }
    }
    __syncthreads();
  }
  #pragma unroll
  for (int mat = 0; mat < 3; ++mat) {
    #pragma unroll
    for (int nt = 0; nt < NTC; ++nt) {
      int nl = nt * 16 + l15;
      bool valid = (nl < NPL);
      #pragma unroll
      for (int j = 0; j < D; ++j) {
        int rt = wvi + 4 * j;
        int i = (rt * 16) >> 6;
        int c = COFF + nl * D + i;
        #pragma unroll
        for (int reg = 0; reg < 4; ++reg) {
          int r = rt * 16 + blk * 4 + reg;
          int q = r & 63;
          if (valid) {
            unsigned short bv = f2bf(acc[mat][nt][j][reg]);
            if (mat == 0)
              *(unsigned short*)(sQ + q * 256 + ((c * 2) ^ ((q & 7) << 4))) = bv;
            else if (mat == 1)
              *(unsigned short*)(sK + q * 256 + ((c * 2) ^ ((q & 7) << 4))) = bv;
            else
              *(unsigned short*)(sVT + c * 128 + ((q * 2) ^ ((c & 7) << 4))) = bv;
          }
        }
      }
    }
  }
}

__launch_bounds__(256, 2)
__global__ void orbattn_fb(const float* __restrict__ x,
                           const unsigned short* __restrict__ ws,
                           float* __restrict__ out) {
  extern __shared__ char smem[];
  char* sX  = smem;
  char* sQ  = smem + 24576;
  char* sK  = smem + 40960;
  char* sVT = smem + 57344;
  char* sP  = smem + 73728;
  int tid = threadIdx.x;
  int bid = blockIdx.x;
  int xcd = bid & 7, t = bid >> 3;
  int h = t & 7;
  int b = (t >> 3) * 8 + xcd;
  const float* xb = x + (size_t)b * 61440;
  float* ob = out + (size_t)b * 61440;
  const int lane = tid & 63, wvi = tid >> 6, l15 = lane & 15, blk = lane >> 4;

  for (int f = tid; f < 512; f += 256) {
    int q = f >> 3, c = 120 + (f & 7);
    *(unsigned short*)(sQ + q * 256 + ((c * 2) ^ ((q & 7) << 4))) = 0;
    *(unsigned short*)(sK + q * 256 + ((c * 2) ^ ((q & 7) << 4))) = 0;
  }

  do_l_fb<256, 1, 32, 2,  0,   0, 7>(xb, ws,          ws + 86016,  ws + 172032, sX, sQ, sK, sVT, h, tid);
  do_l_fb<128, 3, 16, 1, 32, 256, 7>(xb, ws + 65536,  ws + 151552, ws + 237568, sX, sQ, sK, sVT, h, tid);
  do_l_fb< 64, 5,  8, 1, 80, 640, 3>(xb, ws + 81920,  ws + 167936, ws + 253952, sX, sQ, sK, sVT, h, tid);
  __syncthreads();

  f32x4 lacc[4];
  #pragma unroll
  for (int kt = 0; kt < 4; ++kt) lacc[kt] = (f32x4){0.f, 0.f, 0.f, 0.f};
  #pragma unroll
  for (int ks = 0; ks < 4; ++ks) {
    int qr = wvi * 16 + l15;
    int bc = (ks * 32 + blk * 8) * 2;
    short8v qf = *(const short8v*)(sQ + qr * 256 + (bc ^ ((qr & 7) << 4)));
    #pragma unroll
    for (int kt = 0; kt < 4; ++kt) {
      int kr = kt * 16 + l15;
      short8v kf = *(const short8v*)(sK + kr * 256 + (bc ^ ((kr & 7) << 4)));
      lacc[kt] = __builtin_amdgcn_mfma_f32_16x16x32_bf16(qf, kf, lacc[kt], 0, 0, 0);
    }
  }
  #pragma unroll
  for (int reg = 0; reg < 4; ++reg) {
    float mx = fmaxf(fmaxf(lacc[0][reg], lacc[1][reg]), fmaxf(lacc[2][reg], lacc[3][reg]));
    #pragma unroll
    for (int dd = 1; dd <= 8; dd <<= 1) mx = fmaxf(mx, __shfl_xor(mx, dd, 64));
    float p[4], s = 0.f;
    #pragma unroll
    for (int kt = 0; kt < 4; ++kt) { p[kt] = exp2f(lacc[kt][reg] - mx); s += p[kt]; }
    #pragma unroll
    for (int dd = 1; dd <= 8; dd <<= 1) s += __shfl_xor(s, dd, 64);
    float inv = 1.0f / s;
    int q = wvi * 16 + blk * 4 + reg;
    #pragma unroll
    for (int kt = 0; kt < 4; ++kt) {
      int k = kt * 16 + l15;
      *(unsigned short*)(sP + q * 128 + ((k * 2) ^ ((q & 7) << 4))) = f2bf(p[kt] * inv);
    }
  }
  __syncthreads();

  f32x4 uacc[8];
  #pragma unroll
  for (int ct = 0; ct < 8; ++ct) uacc[ct] = (f32x4){0.f, 0.f, 0.f, 0.f};
  #pragma unroll
  for (int ks = 0; ks < 2; ++ks) {
    int qr = wvi * 16 + l15;
    int bc = (ks * 32 + blk * 8) * 2;
    short8v pf = *(const short8v*)(sP + qr * 128 + (bc ^ ((qr & 7) << 4)));
    #pragma unroll
    for (int ct = 0; ct < 8; ++ct) {
      int cr = ct * 16 + l15;
      short8v vf = *(const short8v*)(sVT + cr * 128 + (bc ^ ((cr & 7) << 4)));
      uacc[ct] = __builtin_amdgcn_mfma_f32_16x16x32_bf16(pf, vf, uacc[ct], 0, 0, 0);
    }
  }
  #pragma unroll
  for (int ct = 0; ct < 8; ++ct) {
    int c = ct * 16 + l15;
    if (c < 120) {
      int o;
      if (c < 32) o = h * 32 + c;
      else if (c < 80) { int cc = c - 32; int nl = cc / 3, i = cc - nl * 3; o = 256 + (h * 16 + nl) * 3 + i; }
      else             { int cc = c - 80; int nl = cc / 5, i = cc - nl * 5; o = 640 + (h * 8 + nl) * 5 + i; }
      #pragma unroll
      for (int reg = 0; reg < 4; ++reg) {
        int q = wvi * 16 + blk * 4 + reg;
        int gi = q * 960 + o;
        ob[gi] = xb[gi] + uacc[ct][reg];
      }
    }
  }
}

extern "C" void kernel_launch(void* const* d_in, const int* in_sizes, int n_in,
                              void* d_out, int out_size, void* d_ws, size_t ws_size,
                              hipStream_t stream) {
  const float* x = (const float*)d_in[0];
  unsigned short* wsw = (unsigned short*)d_ws;
  float* out = (float*)d_out;
  prep_w<<<(258048 + 255) / 256, 256, 0, stream>>>(
      (const float*)d_in[1], (const float*)d_in[2], (const float*)d_in[3],
      (const float*)d_in[4], (const float*)d_in[5], (const float*)d_in[6],
      (const float*)d_in[7], (const float*)d_in[8], (const float*)d_in[9], wsw);
  const size_t need = 516096 + (size_t)1024 * 122880;
  if (ws_size >= need) {
    unsigned short* xw = (unsigned short*)((char*)d_ws + 516096);
    conv_x<<<1024, 256, 0, stream>>>(x, xw);
    hipFuncSetAttribute((const void*)orbattn2, hipFuncAttributeMaxDynamicSharedMemorySize, 73728);
    orbattn2<<<8192, 256, 73728, stream>>>(x, wsw, xw, out);
  } else {
    hipFuncSetAttribute((const void*)orbattn_fb, hipFuncAttributeMaxDynamicSharedMemorySize, 81920);
    orbattn_fb<<<8192, 256, 81920, stream>>>(x, wsw, out);
  }
}

// Round 4
// 386.426 us; speedup vs baseline: 2.1041x; 1.2893x over previous
//
#include <hip/hip_runtime.h>
#include <stdint.h>

typedef __attribute__((ext_vector_type(8))) short short8v;
typedef __attribute__((ext_vector_type(4))) float f32x4;

#define ATTN_NORM 0.13363062095621219f
#define LOG2E 1.4426950408889634f

__device__ __forceinline__ unsigned short f2bf(float f) {
  union { float f; uint32_t u; } v; v.f = f;
  uint32_t u = v.u;
  u += 0x7fffu + ((u >> 16) & 1u);
  return (unsigned short)(u >> 16);
}

__device__ __forceinline__ uint32_t pack2bf(float lo, float hi) {
  return (uint32_t)f2bf(lo) | ((uint32_t)f2bf(hi) << 16);
}

// ============ prep: W -> A-fragment-block order, bf16, scales folded ============
// block = 1KB (512 bf16), lane-linear: elem idx = lane*8+e.
// per mat (168 blocks): l0: h*16 + nt*8 + c2*4 + ks   (128 blocks)
//                       l1: 128 + h*4 + c2*2 + ks     (32)
//                       l2: 160 + hp*2 + c2  (hp=h>>1, rows n=hp*16+l15) (8)
__global__ void prep_w2(const float* q0, const float* q1, const float* q2,
                        const float* k0, const float* k1, const float* k2,
                        const float* v0, const float* v1, const float* v2,
                        unsigned short* ws) {
  int e = blockIdx.x * 256 + threadIdx.x;
  if (e >= 258048) return;
  int b = e >> 9, idx = e & 511;
  int lane = idx >> 3, eo = idx & 7;
  int mat = b / 168, r = b - mat * 168;
  int li, n, MUL, c2, ks;
  if (r < 128) {
    li = 0; MUL = 256;
    int h = r >> 4, t = r & 15;
    int nt = t >> 3; c2 = (t >> 2) & 1; ks = t & 3;
    n = h * 32 + nt * 16 + (lane & 15);
  } else if (r < 160) {
    li = 1; MUL = 128;
    int r2 = r - 128; int h = r2 >> 2, t = r2 & 3;
    c2 = t >> 1; ks = t & 1;
    n = h * 16 + (lane & 15);
  } else {
    li = 2; MUL = 64;
    int r2 = r - 160; int hp = r2 >> 1;
    c2 = r2 & 1; ks = 0;
    n = hp * 16 + (lane & 15);
  }
  int m = c2 * (MUL >> 1) + ks * 32 + (lane >> 4) * 8 + eo;
  const float* src;
  if (mat == 0)      src = (li == 0) ? q0 : (li == 1) ? q1 : q2;
  else if (mat == 1) src = (li == 0) ? k0 : (li == 1) ? k1 : k2;
  else               src = (li == 0) ? v0 : (li == 1) ? v1 : v2;
  float scale = (li == 0) ? 0.0625f : (li == 1) ? 0.08838834764831845f : 0.125f;
  if (mat == 0) {
    float qext = (li == 0) ? 1.0f : (li == 1) ? 0.5773502691896258f : 0.4472135954999579f;
    scale *= ATTN_NORM * LOG2E * qext;
  }
  ws[e] = f2bf(src[m * MUL + n] * scale);
}

// ============ conv: x -> B-fragment-block order per batch (120 blocks x 1KB) ====
// block order: l0: c2*16+ks*4+rt (32) | l1: 32+c2*24+ks*12+rt (48) | l2: 80+c2*20+rt (40)
// rt = i*4+qt. content: lane holds token qt*16+(lane&15), m = mb+(lane>>4)*8+e,
// x channel = XO + m*D + i.
__global__ void conv_x2(const float* __restrict__ x, unsigned short* __restrict__ xw) {
  int b = blockIdx.x, tid = threadIdx.x;
  const float* xp = x + (size_t)b * 61440;
  unsigned short* xo = xw + (size_t)b * 61440;
  for (int it = 0; it < 30; ++it) {
    int f = it * 256 + tid;
    int blkid = f >> 6, lane = f & 63;
    int XO, D, mb, i, qt;
    if (blkid < 32) {
      XO = 0; D = 1;
      int c2 = blkid >> 4, t = blkid & 15;
      mb = c2 * 128 + (t >> 2) * 32; i = 0; qt = t & 3;
    } else if (blkid < 80) {
      XO = 256; D = 3;
      int r2 = blkid - 32; int c2 = r2 / 24; int t = r2 - c2 * 24;
      int ks = t / 12; int rt = t - ks * 12;
      mb = c2 * 64 + ks * 32; i = rt >> 2; qt = rt & 3;
    } else {
      XO = 640; D = 5;
      int r2 = blkid - 80; int c2 = r2 / 20; int rt = r2 - c2 * 20;
      mb = c2 * 32; i = rt >> 2; qt = rt & 3;
    }
    int token = qt * 16 + (lane & 15);
    int m0 = mb + (lane >> 4) * 8;
    const float* base = xp + token * 960 + XO + m0 * D + i;
    float v[8];
    if (D == 1) {
      float4 a = *(const float4*)(base);
      float4 c = *(const float4*)(base + 4);
      v[0] = a.x; v[1] = a.y; v[2] = a.z; v[3] = a.w;
      v[4] = c.x; v[5] = c.y; v[6] = c.z; v[7] = c.w;
    } else {
      #pragma unroll
      for (int e2 = 0; e2 < 8; ++e2) v[e2] = base[e2 * D];
    }
    union { unsigned short o[8]; short8v s; } pk;
    #pragma unroll
    for (int e2 = 0; e2 < 8; ++e2) pk.o[e2] = f2bf(v[e2]);
    *(short8v*)(xo + blkid * 512 + lane * 8) = pk.s;
  }
}

// ============ per-l QKV: pure global->reg->MFMA stream, LDS write at end ========
template<int L>
__device__ __forceinline__ void qkv_l(const unsigned short* __restrict__ xwb,
                                      const unsigned short* __restrict__ ws,
                                      char* __restrict__ sQ, char* __restrict__ sK,
                                      char* __restrict__ sVT,
                                      int h, int lane, int wvi) {
  constexpr int D    = (L == 0) ? 1 : (L == 1) ? 3 : 5;
  constexpr int NPL  = (L == 0) ? 32 : (L == 1) ? 16 : 8;
  constexpr int NT   = (L == 0) ? 2 : 1;
  constexpr int KS   = (L == 0) ? 4 : (L == 1) ? 2 : 1;
  constexpr int COFF = (L == 0) ? 0 : (L == 1) ? 32 : 80;
  constexpr int XB   = (L == 0) ? 0 : (L == 1) ? 32 : 80;
  constexpr int XC2  = KS * 4 * D;
  const int l15 = lane & 15, blk = lane >> 4;

  f32x4 acc[3][NT][D];
  #pragma unroll
  for (int a = 0; a < 3; ++a)
    #pragma unroll
    for (int nt = 0; nt < NT; ++nt)
      #pragma unroll
      for (int j = 0; j < D; ++j)
        acc[a][nt][j] = (f32x4){0.f, 0.f, 0.f, 0.f};

  #pragma unroll
  for (int c2 = 0; c2 < 2; ++c2) {
    #pragma unroll
    for (int ks = 0; ks < KS; ++ks) {
      short8v xf[D];
      #pragma unroll
      for (int j = 0; j < D; ++j)
        xf[j] = *(const short8v*)(xwb + (XB + c2 * XC2 + ks * 4 * D + j * 4 + wvi) * 512 + lane * 8);
      #pragma unroll
      for (int mat = 0; mat < 3; ++mat) {
        #pragma unroll
        for (int nt = 0; nt < NT; ++nt) {
          int wb;
          if constexpr (L == 0)      wb = mat * 168 + h * 16 + nt * 8 + c2 * 4 + ks;
          else if constexpr (L == 1) wb = mat * 168 + 128 + h * 4 + c2 * 2 + ks;
          else                       wb = mat * 168 + 160 + (h >> 1) * 2 + c2;
          short8v wf = *(const short8v*)(ws + wb * 512 + lane * 8);
          #pragma unroll
          for (int j = 0; j < D; ++j)
            acc[mat][nt][j] = __builtin_amdgcn_mfma_f32_16x16x32_bf16(wf, xf[j], acc[mat][nt][j], 0, 0, 0);
        }
      }
    }
  }

  const int q = wvi * 16 + l15;
  const int qsw = (q & 7) << 4;
  #pragma unroll
  for (int nt = 0; nt < NT; ++nt) {
    #pragma unroll
    for (int j = 0; j < D; ++j) {
      int cb; bool valid;
      if constexpr (L == 2) { valid = ((blk >> 1) == (h & 1)); cb = COFF + j * NPL + (blk & 1) * 4; }
      else                  { valid = true;                    cb = COFF + j * NPL + nt * 16 + blk * 4; }
      if (valid) {
        uint32_t q01 = pack2bf(acc[0][nt][j][0], acc[0][nt][j][1]);
        uint32_t q23 = pack2bf(acc[0][nt][j][2], acc[0][nt][j][3]);
        uint32_t k01 = pack2bf(acc[1][nt][j][0], acc[1][nt][j][1]);
        uint32_t k23 = pack2bf(acc[1][nt][j][2], acc[1][nt][j][3]);
        int sw = (cb * 2) ^ qsw;
        *(uint2*)(sQ + q * 256 + sw) = make_uint2(q01, q23);
        *(uint2*)(sK + q * 256 + sw) = make_uint2(k01, k23);
        #pragma unroll
        for (int reg = 0; reg < 4; ++reg) {
          int c = cb + reg;
          *(unsigned short*)(sVT + c * 128 + ((q * 2) ^ ((c & 7) << 4))) = f2bf(acc[2][nt][j][reg]);
        }
      }
    }
  }
}

// ============ main attention kernel ============
__launch_bounds__(256, 3)
__global__ void orbattn4(const float* __restrict__ x,
                         const unsigned short* __restrict__ ws,
                         const unsigned short* __restrict__ xw,
                         float* __restrict__ out) {
  extern __shared__ char smem[];
  char* sQ  = smem;           // [64][128] bf16 = 16384
  char* sK  = smem + 16384;   // 16384
  char* sVT = smem + 32768;   // [128][64] bf16 = 16384   total 49152
  char* sP  = smem;           // overlaps sQ (after bar2)
  int tid = threadIdx.x;
  int bid = blockIdx.x;
  // XCD-grouped: all 8 heads of a batch on one XCD (xw[b] L2 reuse)
  int xcd = bid & 7, t = bid >> 3;
  int h = t & 7;
  int b = (t >> 3) * 8 + xcd;
  const float* xb = x + (size_t)b * 61440;
  float* ob = out + (size_t)b * 61440;
  const unsigned short* xwb = xw + (size_t)b * 61440;
  const int lane = tid & 63, wvi = tid >> 6, l15 = lane & 15, blk = lane >> 4;

  // zero pad channels 120..127 of Q,K and rows 120..127 of V^T
  for (int f = tid; f < 512; f += 256) {
    int q = f >> 3, c = 120 + (f & 7);
    int sw = (c * 2) ^ ((q & 7) << 4);
    *(unsigned short*)(sQ + q * 256 + sw) = 0;
    *(unsigned short*)(sK + q * 256 + sw) = 0;
    *(unsigned short*)(sVT + c * 128 + ((q * 2) ^ ((c & 7) << 4))) = 0;
  }

  qkv_l<0>(xwb, ws, sQ, sK, sVT, h, lane, wvi);
  qkv_l<1>(xwb, ws, sQ, sK, sVT, h, lane, wvi);
  qkv_l<2>(xwb, ws, sQ, sK, sVT, h, lane, wvi);
  __syncthreads();   // bar1: QKV in LDS

  // ---- logits: S[q][k] = sum_c Q[q][c] K[k][c]  (wave wvi owns q-tile wvi)
  f32x4 lacc[4];
  #pragma unroll
  for (int kt = 0; kt < 4; ++kt) lacc[kt] = (f32x4){0.f, 0.f, 0.f, 0.f};
  #pragma unroll
  for (int ks = 0; ks < 4; ++ks) {
    int qr = wvi * 16 + l15;
    int bc = (ks * 32 + blk * 8) * 2;
    short8v qf = *(const short8v*)(sQ + qr * 256 + (bc ^ ((qr & 7) << 4)));
    #pragma unroll
    for (int kt = 0; kt < 4; ++kt) {
      int kr = kt * 16 + l15;
      short8v kf = *(const short8v*)(sK + kr * 256 + (bc ^ ((kr & 7) << 4)));
      lacc[kt] = __builtin_amdgcn_mfma_f32_16x16x32_bf16(qf, kf, lacc[kt], 0, 0, 0);
    }
  }
  // ---- softmax over k (exp2; LOG2E folded into wq) -> registers
  float preg[4][4];
  #pragma unroll
  for (int reg = 0; reg < 4; ++reg) {
    float mx = fmaxf(fmaxf(lacc[0][reg], lacc[1][reg]), fmaxf(lacc[2][reg], lacc[3][reg]));
    #pragma unroll
    for (int dd = 1; dd <= 8; dd <<= 1) mx = fmaxf(mx, __shfl_xor(mx, dd, 64));
    float s = 0.f;
    #pragma unroll
    for (int kt = 0; kt < 4; ++kt) { preg[reg][kt] = exp2f(lacc[kt][reg] - mx); s += preg[reg][kt]; }
    #pragma unroll
    for (int dd = 1; dd <= 8; dd <<= 1) s += __shfl_xor(s, dd, 64);
    float inv = 1.0f / s;
    #pragma unroll
    for (int kt = 0; kt < 4; ++kt) preg[reg][kt] *= inv;
  }
  __syncthreads();   // bar2: all sQ reads done; safe to overwrite with P

  #pragma unroll
  for (int reg = 0; reg < 4; ++reg) {
    int q = wvi * 16 + blk * 4 + reg;
    #pragma unroll
    for (int kt = 0; kt < 4; ++kt) {
      int k = kt * 16 + l15;
      *(unsigned short*)(sP + q * 128 + ((k * 2) ^ ((q & 7) << 4))) = f2bf(preg[reg][kt]);
    }
  }
  __syncthreads();   // bar3: P visible (and ordered) before PV reads

  // ---- PV: U[q][c] = sum_k P[q][k] V_T[c][k]
  f32x4 uacc[8];
  #pragma unroll
  for (int ct = 0; ct < 8; ++ct) uacc[ct] = (f32x4){0.f, 0.f, 0.f, 0.f};
  #pragma unroll
  for (int ks = 0; ks < 2; ++ks) {
    int qr = wvi * 16 + l15;
    int bc = (ks * 32 + blk * 8) * 2;
    short8v pf = *(const short8v*)(sP + qr * 128 + (bc ^ ((qr & 7) << 4)));
    #pragma unroll
    for (int ct = 0; ct < 8; ++ct) {
      int cr = ct * 16 + l15;
      short8v vf = *(const short8v*)(sVT + cr * 128 + (bc ^ ((cr & 7) << 4)));
      uacc[ct] = __builtin_amdgcn_mfma_f32_16x16x32_bf16(pf, vf, uacc[ct], 0, 0, 0);
    }
  }
  // ---- epilogue: out = x + update (i-major channel map)
  #pragma unroll
  for (int ct = 0; ct < 8; ++ct) {
    int c = ct * 16 + l15;
    if (c < 120) {
      int o;
      if (c < 32) o = h * 32 + c;
      else if (c < 80) { int cc = c - 32; int i = cc >> 4, nl = cc & 15; o = 256 + (h * 16 + nl) * 3 + i; }
      else             { int cc = c - 80; int i = cc >> 3, nl = cc & 7;  o = 640 + (h * 8 + nl) * 5 + i; }
      #pragma unroll
      for (int reg = 0; reg < 4; ++reg) {
        int q = wvi * 16 + blk * 4 + reg;
        int gi = q * 960 + o;
        ob[gi] = xb[gi] + uacc[ct][reg];
      }
    }
  }
}

extern "C" void kernel_launch(void* const* d_in, const int* in_sizes, int n_in,
                              void* d_out, int out_size, void* d_ws, size_t ws_size,
                              hipStream_t stream) {
  const float* x = (const float*)d_in[0];
  unsigned short* wsw = (unsigned short*)d_ws;                        // 516096 B
  unsigned short* xw = (unsigned short*)((char*)d_ws + 516096);      // ~126 MB
  float* out = (float*)d_out;
  prep_w2<<<1008, 256, 0, stream>>>(
      (const float*)d_in[1], (const float*)d_in[2], (const float*)d_in[3],
      (const float*)d_in[4], (const float*)d_in[5], (const float*)d_in[6],
      (const float*)d_in[7], (const float*)d_in[8], (const float*)d_in[9], wsw);
  conv_x2<<<1024, 256, 0, stream>>>(x, xw);
  hipFuncSetAttribute((const void*)orbattn4, hipFuncAttributeMaxDynamicSharedMemorySize, 49152);
  orbattn4<<<8192, 256, 49152, stream>>>(x, wsw, xw, out);
}